// Round 7
// baseline (104.371 us; speedup 1.0000x reference)
//
#include <hip/hip_runtime.h>
#include <math.h>

#define BATCH   64
#define SEQ     8192
#define NHEAD   8
#define HIDDEN  256
#define TCHUNK  64
#define CHUNKS  128                     // SEQ / TCHUNK
#define BT      4                       // batches per block
#define BGROUPS 16                      // BATCH / BT
#define SCALE   0.17677669529663687f    // 1/sqrt(32)

// ws layout (floats):
#define WS_ALPHA 0
#define WS_M     512
#define WS_RZ    1024
#define WS_ACC   1536                   // S slots of BATCH*HIDDEN floats
#define SLOT_FLOATS (BATCH * HIDDEN)    // 16384

#define CROW  (NHEAD * BT)              // 32 floats per t-row, pad-free conflict-free
#define XPAD  68

// ---------------------------------------------------------------- kernel 1
__global__ void __launch_bounds__(256)
stats_kernel(const float* __restrict__ x,
             const float* __restrict__ qw,
             const float* __restrict__ qb,
             const float* __restrict__ kw,
             float* __restrict__ ws) {
    __shared__ float sA[NHEAD], sC[NHEAD];
    __shared__ float smx[4], smn[4], szz[32];
    int b   = blockIdx.x;
    int tid = threadIdx.x;
    int w   = tid >> 6;
    int lane = tid & 63;

    if (tid < 128) {
        float p1 = qw[tid] * kw[tid];
        float p2 = qb[tid] * kw[tid];
        #pragma unroll
        for (int msk = 1; msk < 16; msk <<= 1) {
            p1 += __shfl_xor(p1, msk);
            p2 += __shfl_xor(p2, msk);
        }
        if ((tid & 15) == 0) { sA[tid >> 4] = p1; sC[tid >> 4] = p2; }
    }

    const float* xb = x + (size_t)b * SEQ;
    float xr[32];
    float mx = -INFINITY, mn = INFINITY;
    #pragma unroll
    for (int i = 0; i < 32; ++i) {
        xr[i] = xb[tid + i * 256];
        mx = fmaxf(mx, xr[i]);
        mn = fminf(mn, xr[i]);
    }
    #pragma unroll
    for (int msk = 32; msk >= 1; msk >>= 1) {
        mx = fmaxf(mx, __shfl_xor(mx, msk));
        mn = fminf(mn, __shfl_xor(mn, msk));
    }
    if (lane == 0) { smx[w] = mx; smn[w] = mn; }
    __syncthreads();

    float xmax = fmaxf(fmaxf(smx[0], smx[1]), fmaxf(smx[2], smx[3]));
    float xmin = fminf(fminf(smn[0], smn[1]), fminf(smn[2], smn[3]));
    float x0 = xb[0];

    float al[NHEAD], mh[NHEAD], ls[NHEAD];
    #pragma unroll
    for (int h = 0; h < NHEAD; ++h) {
        al[h] = SCALE * (x0 * sA[h] + sC[h]);
        mh[h] = fmaxf(al[h] * xmax, al[h] * xmin);
        ls[h] = 0.f;
    }
    #pragma unroll 4
    for (int i = 0; i < 32; ++i) {
        float e = xr[i];
        #pragma unroll
        for (int h = 0; h < NHEAD; ++h)
            ls[h] += __expf(al[h] * e - mh[h]);
    }
    #pragma unroll
    for (int h = 0; h < NHEAD; ++h) {
        float v = ls[h];
        #pragma unroll
        for (int msk = 32; msk >= 1; msk >>= 1)
            v += __shfl_xor(v, msk);
        if (lane == 0) szz[w * NHEAD + h] = v;
    }
    __syncthreads();
    if (tid < NHEAD) {
        float Z = szz[tid] + szz[8 + tid] + szz[16 + tid] + szz[24 + tid];
        ws[WS_ALPHA + b * NHEAD + tid] = al[tid];
        ws[WS_M     + b * NHEAD + tid] = mh[tid];
        ws[WS_RZ    + b * NHEAD + tid] = 1.f / Z;
    }
}

// ---------------------------------------------------------------- zero (atomic fallback only)
__global__ void __launch_bounds__(256)
zero_kernel(float* __restrict__ ws, int nfloats) {
    int idx = blockIdx.x * blockDim.x + threadIdx.x;
    int stride = gridDim.x * blockDim.x;
    for (int i = idx; i < nfloats; i += stride)
        ws[WS_ACC + i] = 0.f;
}

// ---------------------------------------------------------------- kernel 2
// grid (CHUNKS=128, BGROUPS=16) = 2048 blocks, 256 threads.
// __launch_bounds__(256,8): VGPR cap 64 -> 8 waves/SIMD (32 waves/CU, HW max).
// Wave w: t in [w*16,(w+1)*16); lane owns cols lane*4..+3 (head = lane>>3);
// 4 float4 accumulators (one per batch); 3-deep G prefetch.
// Epilogue: 2 barriers (wave w stores accs; then wave w owns batch bi=w).
__global__ void __launch_bounds__(256, 8)
contract_kernel(const float* __restrict__ x,
                const float* __restrict__ G,
                float* __restrict__ ws,
                int S, int use_store) {
    __shared__ float buf[4 * BT * HIDDEN]; // 4096 floats (16KB); first 2048 = coeff
    __shared__ float xs[BT * XPAD];
    __shared__ float sal[BT * NHEAD], smm[BT * NHEAD], srz[BT * NHEAD];
    float* coeff = buf;

    int chunk = blockIdx.x;            // 0..127
    int bg    = blockIdx.y;            // 0..15
    int b0    = bg * BT;
    int tid   = threadIdx.x;
    int w     = tid >> 6;
    int lane  = tid & 63;
    int t0    = chunk * TCHUNK;
    int slot  = chunk % S;

    if (tid < BT * NHEAD) {            // 32 params [bi][h]
        int bi = tid >> 3, hh = tid & 7;
        int g = (b0 + bi) * NHEAD + hh;
        sal[tid] = ws[WS_ALPHA + g];
        smm[tid] = ws[WS_M + g];
        srz[tid] = ws[WS_RZ + g];
    }
    {   // stage x[b0..b0+4)[t0..t0+64) -> xs (256 loads, one per thread)
        int bi = tid >> 6, t = tid & 63;
        xs[bi * XPAD + t] = x[(size_t)(b0 + bi) * SEQ + t0 + t];
    }
    __syncthreads();

    // coeff[t][hh*4+bi] = exp(a*x-m)*rz*x ; 8 t per thread
    {
        int bi  = lane & 3;
        int hh  = (lane >> 2) & 7;
        int sub = lane >> 5;           // 0/1: which 8-t half of the wave's range
        int p   = bi * NHEAD + hh;
        float a  = sal[p], mm = smm[p], rz = srz[p];
        #pragma unroll
        for (int j = 0; j < 8; ++j) {
            int t = w * 16 + sub * 8 + j;
            float e = xs[bi * XPAD + t];
            coeff[t * CROW + hh * 4 + bi] = __expf(a * e - mm) * rz * e;
        }
    }
    __syncthreads();

    int h = lane >> 3;                 // head of this lane's 4 columns
    const float* gp = G + (size_t)(t0 + w * 16) * HIDDEN + lane * 4;
    float4 g0 = *(const float4*)gp;
    float4 g1 = *(const float4*)(gp + HIDDEN);
    float4 g2 = *(const float4*)(gp + 2 * HIDDEN);
    float4 acc[BT];
    #pragma unroll
    for (int bi = 0; bi < BT; ++bi) acc[bi] = make_float4(0.f, 0.f, 0.f, 0.f);

    #pragma unroll
    for (int t = 0; t < 16; ++t) {
        float4 gn = (t + 3 < 16) ? *(const float4*)(gp + (size_t)(t + 3) * HIDDEN)
                                 : g2;                       // 3-deep prefetch
        float4 c = *(const float4*)(coeff + (w * 16 + t) * CROW + h * 4);
        acc[0].x = fmaf(c.x, g0.x, acc[0].x);
        acc[0].y = fmaf(c.x, g0.y, acc[0].y);
        acc[0].z = fmaf(c.x, g0.z, acc[0].z);
        acc[0].w = fmaf(c.x, g0.w, acc[0].w);
        acc[1].x = fmaf(c.y, g0.x, acc[1].x);
        acc[1].y = fmaf(c.y, g0.y, acc[1].y);
        acc[1].z = fmaf(c.y, g0.z, acc[1].z);
        acc[1].w = fmaf(c.y, g0.w, acc[1].w);
        acc[2].x = fmaf(c.z, g0.x, acc[2].x);
        acc[2].y = fmaf(c.z, g0.y, acc[2].y);
        acc[2].z = fmaf(c.z, g0.z, acc[2].z);
        acc[2].w = fmaf(c.z, g0.w, acc[2].w);
        acc[3].x = fmaf(c.w, g0.x, acc[3].x);
        acc[3].y = fmaf(c.w, g0.y, acc[3].y);
        acc[3].z = fmaf(c.w, g0.z, acc[3].z);
        acc[3].w = fmaf(c.w, g0.w, acc[3].w);
        g0 = g1; g1 = g2; g2 = gn;
    }

    // 2-barrier epilogue: wave w dumps its 4 accs; then wave w owns batch bi=w.
    __syncthreads();                   // coeff reads done
    #pragma unroll
    for (int bi = 0; bi < BT; ++bi)
        *(float4*)(buf + (w * BT + bi) * HIDDEN + lane * 4) = acc[bi];
    __syncthreads();
    {
        int bi = w;                    // wave w reduces batch bi=w across 4 waves
        float4 s0 = *(const float4*)(buf + (0 * BT + bi) * HIDDEN + lane * 4);
        float4 s1 = *(const float4*)(buf + (1 * BT + bi) * HIDDEN + lane * 4);
        float4 s2 = *(const float4*)(buf + (2 * BT + bi) * HIDDEN + lane * 4);
        float4 s3 = *(const float4*)(buf + (3 * BT + bi) * HIDDEN + lane * 4);
        float4 r = make_float4((s0.x + s1.x) + (s2.x + s3.x),
                               (s0.y + s1.y) + (s2.y + s3.y),
                               (s0.z + s1.z) + (s2.z + s3.z),
                               (s0.w + s1.w) + (s2.w + s3.w));
        float* dst = ws + WS_ACC + (size_t)slot * SLOT_FLOATS
                   + (size_t)(b0 + bi) * HIDDEN + lane * 4;
        if (use_store) {
            *(float4*)dst = r;
        } else {
            atomicAdd(dst + 0, r.x);
            atomicAdd(dst + 1, r.y);
            atomicAdd(dst + 2, r.z);
            atomicAdd(dst + 3, r.w);
        }
    }
}

// ---------------------------------------------------------------- kernel 3
// 1024 threads: 4 threads per column split the S-slot sum, then 256 threads
// bitonic-sort descending.
__global__ void __launch_bounds__(1024)
reduce_sort_kernel(const float* __restrict__ ws,
                   float* __restrict__ out, int S) {
    __shared__ float v[HIDDEN];
    __shared__ float pq[3][HIDDEN];
    int b   = blockIdx.x;
    int tid = threadIdx.x;
    int c   = tid & 255;
    int q   = tid >> 8;                // 0..3
    float s = 0.f;
    #pragma unroll 4
    for (int sl = q; sl < S; sl += 4)
        s += ws[WS_ACC + (size_t)sl * SLOT_FLOATS + (size_t)b * HIDDEN + c];
    if (q) pq[q - 1][c] = s;
    __syncthreads();
    if (q == 0) v[c] = (s + pq[0][c]) + (pq[1][c] + pq[2][c]);
    __syncthreads();

    for (int k = 2; k <= HIDDEN; k <<= 1) {
        for (int j = k >> 1; j > 0; j >>= 1) {
            if (tid < 256) {
                int ixj = tid ^ j;
                if (ixj > tid) {
                    float a  = v[tid];
                    float bb = v[ixj];
                    bool up  = (tid & k) == 0;
                    if (up ? (a < bb) : (a > bb)) {
                        v[tid] = bb;
                        v[ixj] = a;
                    }
                }
            }
            __syncthreads();
        }
    }
    if (tid < 256) out[(size_t)b * HIDDEN + tid] = v[tid];
}

// ---------------------------------------------------------------- launcher
extern "C" void kernel_launch(void* const* d_in, const int* in_sizes, int n_in,
                              void* d_out, int out_size, void* d_ws, size_t ws_size,
                              hipStream_t stream) {
    const float* x  = (const float*)d_in[0];   // (64, 8192, 1)
    const float* qw = (const float*)d_in[1];   // (128,1)
    const float* qb = (const float*)d_in[2];   // (128,)
    const float* kw = (const float*)d_in[3];   // (128,1)
    // d_in[4] = k_b (cancels in softmax)
    const float* G  = (const float*)d_in[5];   // (8192, 256)
    float* out = (float*)d_out;
    float* ws  = (float*)d_ws;

    long avail = (long)(ws_size / 4) - WS_ACC;
    int S = (int)(avail / SLOT_FLOATS);
    if (S > CHUNKS) S = CHUNKS;
    if (S < 1) S = 1;
    int use_store = (S == CHUNKS) ? 1 : 0;

    stats_kernel<<<BATCH, 256, 0, stream>>>(x, qw, qb, kw, ws);
    if (!use_store)
        zero_kernel<<<256, 256, 0, stream>>>(ws, S * SLOT_FLOATS);
    contract_kernel<<<dim3(CHUNKS, BGROUPS), 256, 0, stream>>>(x, G, ws, S, use_store);
    reduce_sort_kernel<<<BATCH, 1024, 0, stream>>>(ws, out, S);
}

// Round 8
// 92.321 us; speedup vs baseline: 1.1305x; 1.1305x over previous
//
#include <hip/hip_runtime.h>
#include <math.h>

#define BATCH   64
#define SEQ     8192
#define NHEAD   8
#define HIDDEN  256
#define TCHUNK  64
#define CHUNKS  128                     // SEQ / TCHUNK
#define BT      4                       // batches per block
#define BGROUPS 16                      // BATCH / BT
#define SCALE   0.17677669529663687f    // 1/sqrt(32)

// ws layout (floats):
#define WS_ALPHA 0
#define WS_M     512
#define WS_RZ    1024
#define WS_ACC   1536                   // S slots of BATCH*HIDDEN floats
#define SLOT_FLOATS (BATCH * HIDDEN)    // 16384

#define CROW  (NHEAD * BT)              // 32 floats per t-row, pad-free conflict-free
#define XPAD  68

// ---------------------------------------------------------------- kernel 1
__global__ void __launch_bounds__(256)
stats_kernel(const float* __restrict__ x,
             const float* __restrict__ qw,
             const float* __restrict__ qb,
             const float* __restrict__ kw,
             float* __restrict__ ws) {
    __shared__ float sA[NHEAD], sC[NHEAD];
    __shared__ float smx[4], smn[4], szz[32];
    int b   = blockIdx.x;
    int tid = threadIdx.x;
    int w   = tid >> 6;
    int lane = tid & 63;

    if (tid < 128) {
        float p1 = qw[tid] * kw[tid];
        float p2 = qb[tid] * kw[tid];
        #pragma unroll
        for (int msk = 1; msk < 16; msk <<= 1) {
            p1 += __shfl_xor(p1, msk);
            p2 += __shfl_xor(p2, msk);
        }
        if ((tid & 15) == 0) { sA[tid >> 4] = p1; sC[tid >> 4] = p2; }
    }

    const float* xb = x + (size_t)b * SEQ;
    float xr[32];
    float mx = -INFINITY, mn = INFINITY;
    #pragma unroll
    for (int i = 0; i < 32; ++i) {
        xr[i] = xb[tid + i * 256];
        mx = fmaxf(mx, xr[i]);
        mn = fminf(mn, xr[i]);
    }
    #pragma unroll
    for (int msk = 32; msk >= 1; msk >>= 1) {
        mx = fmaxf(mx, __shfl_xor(mx, msk));
        mn = fminf(mn, __shfl_xor(mn, msk));
    }
    if (lane == 0) { smx[w] = mx; smn[w] = mn; }
    __syncthreads();

    float xmax = fmaxf(fmaxf(smx[0], smx[1]), fmaxf(smx[2], smx[3]));
    float xmin = fminf(fminf(smn[0], smn[1]), fminf(smn[2], smn[3]));
    float x0 = xb[0];

    float al[NHEAD], mh[NHEAD], ls[NHEAD];
    #pragma unroll
    for (int h = 0; h < NHEAD; ++h) {
        al[h] = SCALE * (x0 * sA[h] + sC[h]);
        mh[h] = fmaxf(al[h] * xmax, al[h] * xmin);
        ls[h] = 0.f;
    }
    #pragma unroll 4
    for (int i = 0; i < 32; ++i) {
        float e = xr[i];
        #pragma unroll
        for (int h = 0; h < NHEAD; ++h)
            ls[h] += __expf(al[h] * e - mh[h]);
    }
    #pragma unroll
    for (int h = 0; h < NHEAD; ++h) {
        float v = ls[h];
        #pragma unroll
        for (int msk = 32; msk >= 1; msk >>= 1)
            v += __shfl_xor(v, msk);
        if (lane == 0) szz[w * NHEAD + h] = v;
    }
    __syncthreads();
    if (tid < NHEAD) {
        float Z = szz[tid] + szz[8 + tid] + szz[16 + tid] + szz[24 + tid];
        ws[WS_ALPHA + b * NHEAD + tid] = al[tid];
        ws[WS_M     + b * NHEAD + tid] = mh[tid];
        ws[WS_RZ    + b * NHEAD + tid] = 1.f / Z;
    }
}

// ---------------------------------------------------------------- zero (atomic fallback only)
__global__ void __launch_bounds__(256)
zero_kernel(float* __restrict__ ws, int nfloats) {
    int idx = blockIdx.x * blockDim.x + threadIdx.x;
    int stride = gridDim.x * blockDim.x;
    for (int i = idx; i < nfloats; i += stride)
        ws[WS_ACC + i] = 0.f;
}

// ---------------------------------------------------------------- kernel 2
// grid (CHUNKS=128, BGROUPS=16) = 2048 blocks, 256 threads, (256,4): cap 128 VGPR.
// Key change vs R6: ALL 16 G rows loaded up front into 64 VGPRs -> 16-deep MLP,
// issued before the exp/coeff phase so the ~900cyc cold-G latency hides behind
// x-staging + exp + barrier. Wave w: t in [w*16,(w+1)*16); lane owns cols
// lane*4..+3 (head = lane>>3); 4 float4 accumulators. 2-barrier epilogue.
__global__ void __launch_bounds__(256, 4)
contract_kernel(const float* __restrict__ x,
                const float* __restrict__ G,
                float* __restrict__ ws,
                int S, int use_store) {
    __shared__ float buf[4 * BT * HIDDEN]; // 4096 floats (16KB); first 2048 = coeff
    __shared__ float xs[BT * XPAD];
    __shared__ float sal[BT * NHEAD], smm[BT * NHEAD], srz[BT * NHEAD];
    float* coeff = buf;

    int chunk = blockIdx.x;            // 0..127
    int bg    = blockIdx.y;            // 0..15
    int b0    = bg * BT;
    int tid   = threadIdx.x;
    int w     = tid >> 6;
    int lane  = tid & 63;
    int t0    = chunk * TCHUNK;
    int slot  = chunk % S;

    if (tid < BT * NHEAD) {            // 32 params [bi][h]
        int bi = tid >> 3, hh = tid & 7;
        int gi = (b0 + bi) * NHEAD + hh;
        sal[tid] = ws[WS_ALPHA + gi];
        smm[tid] = ws[WS_M + gi];
        srz[tid] = ws[WS_RZ + gi];
    }
    {   // stage x[b0..b0+4)[t0..t0+64) -> xs (256 loads, one per thread)
        int bi = tid >> 6, t = tid & 63;
        xs[bi * XPAD + t] = x[(size_t)(b0 + bi) * SEQ + t0 + t];
    }

    // issue ALL 16 G-row loads now (independent, 16-deep in flight)
    const float* gp = G + (size_t)(t0 + w * 16) * HIDDEN + lane * 4;
    float4 g[16];
    #pragma unroll
    for (int t = 0; t < 16; ++t)
        g[t] = *(const float4*)(gp + (size_t)t * HIDDEN);

    __syncthreads();

    // coeff[t][hh*4+bi] = exp(a*x-m)*rz*x ; 8 t per thread
    {
        int bi  = lane & 3;
        int hh  = (lane >> 2) & 7;
        int sub = lane >> 5;           // 0/1: which 8-t half of the wave's range
        int p   = bi * NHEAD + hh;
        float a  = sal[p], mm = smm[p], rz = srz[p];
        #pragma unroll
        for (int j = 0; j < 8; ++j) {
            int t = w * 16 + sub * 8 + j;
            float e = xs[bi * XPAD + t];
            coeff[t * CROW + hh * 4 + bi] = __expf(a * e - mm) * rz * e;
        }
    }
    __syncthreads();

    int h = lane >> 3;                 // head of this lane's 4 columns
    float4 acc[BT];
    #pragma unroll
    for (int bi = 0; bi < BT; ++bi) acc[bi] = make_float4(0.f, 0.f, 0.f, 0.f);

    #pragma unroll
    for (int t = 0; t < 16; ++t) {
        float4 c = *(const float4*)(coeff + (w * 16 + t) * CROW + h * 4);
        acc[0].x = fmaf(c.x, g[t].x, acc[0].x);
        acc[0].y = fmaf(c.x, g[t].y, acc[0].y);
        acc[0].z = fmaf(c.x, g[t].z, acc[0].z);
        acc[0].w = fmaf(c.x, g[t].w, acc[0].w);
        acc[1].x = fmaf(c.y, g[t].x, acc[1].x);
        acc[1].y = fmaf(c.y, g[t].y, acc[1].y);
        acc[1].z = fmaf(c.y, g[t].z, acc[1].z);
        acc[1].w = fmaf(c.y, g[t].w, acc[1].w);
        acc[2].x = fmaf(c.z, g[t].x, acc[2].x);
        acc[2].y = fmaf(c.z, g[t].y, acc[2].y);
        acc[2].z = fmaf(c.z, g[t].z, acc[2].z);
        acc[2].w = fmaf(c.z, g[t].w, acc[2].w);
        acc[3].x = fmaf(c.w, g[t].x, acc[3].x);
        acc[3].y = fmaf(c.w, g[t].y, acc[3].y);
        acc[3].z = fmaf(c.w, g[t].z, acc[3].z);
        acc[3].w = fmaf(c.w, g[t].w, acc[3].w);
    }

    // 2-barrier epilogue: wave w dumps its 4 accs; then wave w owns batch bi=w.
    __syncthreads();                   // coeff reads done
    #pragma unroll
    for (int bi = 0; bi < BT; ++bi)
        *(float4*)(buf + (w * BT + bi) * HIDDEN + lane * 4) = acc[bi];
    __syncthreads();
    {
        int bi = w;                    // wave w reduces batch bi=w across 4 waves
        float4 s0 = *(const float4*)(buf + (0 * BT + bi) * HIDDEN + lane * 4);
        float4 s1 = *(const float4*)(buf + (1 * BT + bi) * HIDDEN + lane * 4);
        float4 s2 = *(const float4*)(buf + (2 * BT + bi) * HIDDEN + lane * 4);
        float4 s3 = *(const float4*)(buf + (3 * BT + bi) * HIDDEN + lane * 4);
        float4 r = make_float4((s0.x + s1.x) + (s2.x + s3.x),
                               (s0.y + s1.y) + (s2.y + s3.y),
                               (s0.z + s1.z) + (s2.z + s3.z),
                               (s0.w + s1.w) + (s2.w + s3.w));
        float* dst = ws + WS_ACC + (size_t)slot * SLOT_FLOATS
                   + (size_t)(b0 + bi) * HIDDEN + lane * 4;
        if (use_store) {
            *(float4*)dst = r;
        } else {
            atomicAdd(dst + 0, r.x);
            atomicAdd(dst + 1, r.y);
            atomicAdd(dst + 2, r.z);
            atomicAdd(dst + 3, r.w);
        }
    }
}

// ---------------------------------------------------------------- kernel 3
// 1024 threads: 4 threads per column split the S-slot sum, then 256 threads
// bitonic-sort descending.
__global__ void __launch_bounds__(1024)
reduce_sort_kernel(const float* __restrict__ ws,
                   float* __restrict__ out, int S) {
    __shared__ float v[HIDDEN];
    __shared__ float pq[3][HIDDEN];
    int b   = blockIdx.x;
    int tid = threadIdx.x;
    int c   = tid & 255;
    int q   = tid >> 8;                // 0..3
    float s = 0.f;
    #pragma unroll 4
    for (int sl = q; sl < S; sl += 4)
        s += ws[WS_ACC + (size_t)sl * SLOT_FLOATS + (size_t)b * HIDDEN + c];
    if (q) pq[q - 1][c] = s;
    __syncthreads();
    if (q == 0) v[c] = (s + pq[0][c]) + (pq[1][c] + pq[2][c]);
    __syncthreads();

    for (int k = 2; k <= HIDDEN; k <<= 1) {
        for (int j = k >> 1; j > 0; j >>= 1) {
            if (tid < 256) {
                int ixj = tid ^ j;
                if (ixj > tid) {
                    float a  = v[tid];
                    float bb = v[ixj];
                    bool up  = (tid & k) == 0;
                    if (up ? (a < bb) : (a > bb)) {
                        v[tid] = bb;
                        v[ixj] = a;
                    }
                }
            }
            __syncthreads();
        }
    }
    if (tid < 256) out[(size_t)b * HIDDEN + tid] = v[tid];
}

// ---------------------------------------------------------------- launcher
extern "C" void kernel_launch(void* const* d_in, const int* in_sizes, int n_in,
                              void* d_out, int out_size, void* d_ws, size_t ws_size,
                              hipStream_t stream) {
    const float* x  = (const float*)d_in[0];   // (64, 8192, 1)
    const float* qw = (const float*)d_in[1];   // (128,1)
    const float* qb = (const float*)d_in[2];   // (128,)
    const float* kw = (const float*)d_in[3];   // (128,1)
    // d_in[4] = k_b (cancels in softmax)
    const float* G  = (const float*)d_in[5];   // (8192, 256)
    float* out = (float*)d_out;
    float* ws  = (float*)d_ws;

    long avail = (long)(ws_size / 4) - WS_ACC;
    int S = (int)(avail / SLOT_FLOATS);
    if (S > CHUNKS) S = CHUNKS;
    if (S < 1) S = 1;
    int use_store = (S == CHUNKS) ? 1 : 0;

    stats_kernel<<<BATCH, 256, 0, stream>>>(x, qw, qb, kw, ws);
    if (!use_store)
        zero_kernel<<<256, 256, 0, stream>>>(ws, S * SLOT_FLOATS);
    contract_kernel<<<dim3(CHUNKS, BGROUPS), 256, 0, stream>>>(x, G, ws, S, use_store);
    reduce_sort_kernel<<<BATCH, 1024, 0, stream>>>(ws, out, S);
}

// Round 9
// 82.583 us; speedup vs baseline: 1.2638x; 1.1179x over previous
//
#include <hip/hip_runtime.h>
#include <math.h>

#define BATCH   64
#define SEQ     8192
#define NHEAD   8
#define HIDDEN  256
#define SCALE   0.17677669529663687f    // 1/sqrt(32)
#define TPB     1024
#define NW      16                      // waves per block
// t* = c * (8191/255); window t in [ceil(t*-8), t*+8]; 17 slots, 4-way split
#define TSCALE  32.121568627450980f     // 8191/255
#define WINR    8.0f

// Sparse-G fused kernel: one block per batch.
// Phase 0: issue <=5 scattered G loads per thread (hidden behind phases 1-2).
// Phase 1: stage x[b,:] to LDS; per-thread min/max; head consts A,C (tid<128).
// Phase 2: alpha/m per head (all threads, uniform); Z over all 8192 t (exact
//          softmax denominator); broadcast 1/Z via LDS.
// Phase 3: thread (c=tid&255, q=tid>>8) sums its <=5 window terms
//          exp(a*x_t-m)*x_t*G[t,c]; combine 4 q-partials in LDS.
// Phase 4: rank sort (descending, index tie-break) -> out.
__global__ void __launch_bounds__(TPB)
fused_kernel(const float* __restrict__ x,
             const float* __restrict__ qw,
             const float* __restrict__ qb,
             const float* __restrict__ kw,
             const float* __restrict__ G,
             float* __restrict__ out) {
    __shared__ float xsh[SEQ];          // 32 KB
    __shared__ float sA[NHEAD], sC[NHEAD];
    __shared__ float smx[NW], smn[NW];
    __shared__ float red[NW * NHEAD];
    __shared__ float rzs[NHEAD];
    __shared__ float pq[3][HIDDEN];
    __shared__ float vv[HIDDEN];

    int b    = blockIdx.x;
    int tid  = threadIdx.x;
    int w    = tid >> 6;
    int lane = tid & 63;
    int c    = tid & 255;
    int q    = tid >> 8;                // 0..3

    // ---- phase 0: early scattered G loads for this (c,q) ----
    float tc   = (float)c * TSCALE;
    int   t_lo = (int)ceilf(tc - WINR);
    float gv[5];
    int   tt[5];
    #pragma unroll
    for (int k = 0; k < 5; ++k) {
        int j = q + 4 * k;              // 0..16 (j=17..19 invalid for q>0,k=4)
        int t = t_lo + j;
        bool valid = (j < 17) && (t >= 0) && (t < SEQ);
        tt[k] = valid ? t : -1;
        gv[k] = 0.f;
        if (valid) gv[k] = G[(size_t)t * HIDDEN + c];
    }

    // ---- phase 1: stage x, local min/max, head consts ----
    const float* xb = x + (size_t)b * SEQ;
    float xr[8];
    float mx = -INFINITY, mn = INFINITY;
    #pragma unroll
    for (int i = 0; i < 8; ++i) {
        float f = xb[tid + i * TPB];
        xr[i] = f;
        xsh[tid + i * TPB] = f;
        mx = fmaxf(mx, f);
        mn = fminf(mn, f);
    }
    if (tid < 128) {                    // A_h = sum qw*kw, C_h = sum qb*kw
        float p1 = qw[tid] * kw[tid];
        float p2 = qb[tid] * kw[tid];
        #pragma unroll
        for (int msk = 1; msk < 16; msk <<= 1) {
            p1 += __shfl_xor(p1, msk);
            p2 += __shfl_xor(p2, msk);
        }
        if ((tid & 15) == 0) { sA[tid >> 4] = p1; sC[tid >> 4] = p2; }
    }
    #pragma unroll
    for (int msk = 32; msk >= 1; msk >>= 1) {
        mx = fmaxf(mx, __shfl_xor(mx, msk));
        mn = fminf(mn, __shfl_xor(mn, msk));
    }
    if (lane == 0) { smx[w] = mx; smn[w] = mn; }
    __syncthreads();

    // ---- phase 2: alpha, m, Z ----
    float xmax = smx[0], xmin = smn[0];
    #pragma unroll
    for (int i = 1; i < NW; ++i) {
        xmax = fmaxf(xmax, smx[i]);
        xmin = fminf(xmin, smn[i]);
    }
    float x0 = xsh[0];
    float al[NHEAD], mh[NHEAD], ls[NHEAD];
    #pragma unroll
    for (int h = 0; h < NHEAD; ++h) {
        al[h] = SCALE * (x0 * sA[h] + sC[h]);
        mh[h] = fmaxf(al[h] * xmax, al[h] * xmin);  // = max_t alpha*x_t
        ls[h] = 0.f;
    }
    #pragma unroll
    for (int i = 0; i < 8; ++i) {
        float e = xr[i];
        #pragma unroll
        for (int h = 0; h < NHEAD; ++h)
            ls[h] += __expf(al[h] * e - mh[h]);
    }
    #pragma unroll
    for (int h = 0; h < NHEAD; ++h) {
        float v = ls[h];
        #pragma unroll
        for (int msk = 32; msk >= 1; msk >>= 1)
            v += __shfl_xor(v, msk);
        if (lane == 0) red[w * NHEAD + h] = v;
    }
    __syncthreads();
    if (tid < NHEAD) {
        float Z = 0.f;
        #pragma unroll
        for (int i = 0; i < NW; ++i) Z += red[i * NHEAD + tid];
        rzs[tid] = 1.f / Z;
    }
    __syncthreads();

    // ---- phase 3: windowed column sum ----
    {
        int h = c >> 5;
        float a = al[h], m = mh[h], rz = rzs[h];
        float s = 0.f;
        #pragma unroll
        for (int k = 0; k < 5; ++k) {
            if (tt[k] >= 0) {
                float e = xsh[tt[k]];
                s += __expf(a * e - m) * e * gv[k];
            }
        }
        s *= rz;
        if (q) pq[q - 1][c] = s;
        __syncthreads();
        if (q == 0) vv[c] = (s + pq[0][c]) + (pq[1][c] + pq[2][c]);
        __syncthreads();
    }

    // ---- phase 4: rank sort, descending ----
    if (tid < HIDDEN) {
        float v = vv[tid];
        int rank = 0;
        for (int j = 0; j < HIDDEN; ++j) {
            float u = vv[j];
            rank += (u > v) || (u == v && j < tid);
        }
        out[(size_t)b * HIDDEN + rank] = v;
    }
}

// ---------------------------------------------------------------- launcher
extern "C" void kernel_launch(void* const* d_in, const int* in_sizes, int n_in,
                              void* d_out, int out_size, void* d_ws, size_t ws_size,
                              hipStream_t stream) {
    const float* x  = (const float*)d_in[0];   // (64, 8192, 1)
    const float* qw = (const float*)d_in[1];   // (128,1)
    const float* qb = (const float*)d_in[2];   // (128,)
    const float* kw = (const float*)d_in[3];   // (128,1)
    // d_in[4] = k_b (cancels in softmax)
    const float* G  = (const float*)d_in[5];   // (8192, 256)
    float* out = (float*)d_out;

    fused_kernel<<<BATCH, TPB, 0, stream>>>(x, qw, qb, kw, G, out);
}

// Round 10
// 81.571 us; speedup vs baseline: 1.2795x; 1.0124x over previous
//
#include <hip/hip_runtime.h>
#include <math.h>

#define BATCH   64
#define SEQ     8192
#define NHEAD   8
#define HIDDEN  256
#define SCALE   0.17677669529663687f    // 1/sqrt(32)
#define TPB     1024
#define NW      16                      // waves per block
#define QUARTERS 4                      // blocks per batch (each writes 64 cols)
// t* = c * (8191/255); window t in [ceil(t*-8), t*+8]; 17 slots, 4-way split
#define TSCALE  32.121568627450980f     // 8191/255
#define WINR    8.0f

// Sparse-G fused kernel: grid (BATCH, QUARTERS); blocks of one batch compute
// phases 0-3 redundantly (cheap), each writes its own 64-column quarter of the
// rank-sorted output (4x CU parallelism on the latency-bound critical path).
__global__ void __launch_bounds__(TPB)
fused_kernel(const float* __restrict__ x,
             const float* __restrict__ qw,
             const float* __restrict__ qb,
             const float* __restrict__ kw,
             const float* __restrict__ G,
             float* __restrict__ out) {
    __shared__ float xsh[SEQ];          // 32 KB
    __shared__ float sA[NHEAD], sC[NHEAD];
    __shared__ float smx[NW], smn[NW];
    __shared__ float red[NW * NHEAD];
    __shared__ float rzs[NHEAD];
    __shared__ float pq[3][HIDDEN];
    __shared__ float vv[HIDDEN];

    int b    = blockIdx.x;
    int quar = blockIdx.y;              // 0..3: which 64 output ranks we write
    int tid  = threadIdx.x;
    int w    = tid >> 6;
    int lane = tid & 63;
    int c    = tid & 255;
    int q    = tid >> 8;                // 0..3

    // ---- phase 0: early scattered G loads for this (c,q) ----
    float tc   = (float)c * TSCALE;
    int   t_lo = (int)ceilf(tc - WINR);
    float gv[5];
    int   tt[5];
    #pragma unroll
    for (int k = 0; k < 5; ++k) {
        int j = q + 4 * k;              // 0..16
        int t = t_lo + j;
        bool valid = (j < 17) && (t >= 0) && (t < SEQ);
        tt[k] = valid ? t : -1;
        gv[k] = 0.f;
        if (valid) gv[k] = G[(size_t)t * HIDDEN + c];
    }

    // ---- phase 1: stage x, local min/max, head consts ----
    const float* xb = x + (size_t)b * SEQ;
    float xr[8];
    float mx = -INFINITY, mn = INFINITY;
    #pragma unroll
    for (int i = 0; i < 8; ++i) {
        float f = xb[tid + i * TPB];
        xr[i] = f;
        xsh[tid + i * TPB] = f;
        mx = fmaxf(mx, f);
        mn = fminf(mn, f);
    }
    if (tid < 128) {                    // A_h = sum qw*kw, C_h = sum qb*kw
        float p1 = qw[tid] * kw[tid];
        float p2 = qb[tid] * kw[tid];
        #pragma unroll
        for (int msk = 1; msk < 16; msk <<= 1) {
            p1 += __shfl_xor(p1, msk);
            p2 += __shfl_xor(p2, msk);
        }
        if ((tid & 15) == 0) { sA[tid >> 4] = p1; sC[tid >> 4] = p2; }
    }
    #pragma unroll
    for (int msk = 32; msk >= 1; msk >>= 1) {
        mx = fmaxf(mx, __shfl_xor(mx, msk));
        mn = fminf(mn, __shfl_xor(mn, msk));
    }
    if (lane == 0) { smx[w] = mx; smn[w] = mn; }
    __syncthreads();

    // ---- phase 2: alpha, m, Z ----
    float xmax = smx[0], xmin = smn[0];
    #pragma unroll
    for (int i = 1; i < NW; ++i) {
        xmax = fmaxf(xmax, smx[i]);
        xmin = fminf(xmin, smn[i]);
    }
    float x0 = xsh[0];
    float al[NHEAD], mh[NHEAD], ls[NHEAD];
    #pragma unroll
    for (int h = 0; h < NHEAD; ++h) {
        al[h] = SCALE * (x0 * sA[h] + sC[h]);
        mh[h] = fmaxf(al[h] * xmax, al[h] * xmin);  // = max_t alpha*x_t
        ls[h] = 0.f;
    }
    #pragma unroll
    for (int i = 0; i < 8; ++i) {
        float e = xr[i];
        #pragma unroll
        for (int h = 0; h < NHEAD; ++h)
            ls[h] += __expf(al[h] * e - mh[h]);
    }
    #pragma unroll
    for (int h = 0; h < NHEAD; ++h) {
        float v = ls[h];
        #pragma unroll
        for (int msk = 32; msk >= 1; msk >>= 1)
            v += __shfl_xor(v, msk);
        if (lane == 0) red[w * NHEAD + h] = v;
    }
    __syncthreads();
    if (tid < NHEAD) {
        float Z = 0.f;
        #pragma unroll
        for (int i = 0; i < NW; ++i) Z += red[i * NHEAD + tid];
        rzs[tid] = 1.f / Z;
    }
    __syncthreads();

    // ---- phase 3: windowed column sum (all 256 columns; needed for ranks) ----
    {
        int h = c >> 5;
        float a = al[h], m = mh[h], rz = rzs[h];
        float s = 0.f;
        #pragma unroll
        for (int k = 0; k < 5; ++k) {
            if (tt[k] >= 0) {
                float e = xsh[tt[k]];
                s += __expf(a * e - m) * e * gv[k];
            }
        }
        s *= rz;
        if (q) pq[q - 1][c] = s;
        __syncthreads();
        if (q == 0) vv[c] = (s + pq[0][c]) + (pq[1][c] + pq[2][c]);
        __syncthreads();
    }

    // ---- phase 4: rank sort (descending); this block writes cols of its quarter ----
    if (tid < 64) {
        int cc = quar * 64 + tid;
        float v = vv[cc];
        int rank = 0;
        #pragma unroll 8
        for (int j = 0; j < HIDDEN; ++j) {
            float u = vv[j];
            rank += (u > v) || (u == v && j < cc);
        }
        out[(size_t)b * HIDDEN + rank] = v;
    }
}

// ---------------------------------------------------------------- launcher
extern "C" void kernel_launch(void* const* d_in, const int* in_sizes, int n_in,
                              void* d_out, int out_size, void* d_ws, size_t ws_size,
                              hipStream_t stream) {
    const float* x  = (const float*)d_in[0];   // (64, 8192, 1)
    const float* qw = (const float*)d_in[1];   // (128,1)
    const float* qb = (const float*)d_in[2];   // (128,)
    const float* kw = (const float*)d_in[3];   // (128,1)
    // d_in[4] = k_b (cancels in softmax)
    const float* G  = (const float*)d_in[5];   // (8192, 256)
    float* out = (float*)d_out;

    fused_kernel<<<dim3(BATCH, QUARTERS), TPB, 0, stream>>>(x, qw, qb, kw, G, out);
}